// Round 2
// 23430.212 us; speedup vs baseline: 1.6873x; 1.6873x over previous
//
#include <hip/hip_runtime.h>

// Reference chain is numpy float64 (verified: absmax == 0 with exact f64 mirror).
// Distances/min/argmax computed in f64; no contraction anywhere.
#pragma clang fp contract(off)

#define BATCH  16
#define NPT    32768
#define NPOINT 2048
#define G      16            // blocks per batch
#define TPB    256
#define PPT    8             // points per thread; G*TPB*PPT == NPT
#define NWAVES (TPB/64)

// Cross-block communication record: one per (buf, batch, sub-block).
// Winner block publishes {f64 best, idx, winner coords}; seq (=it+1) is the
// release flag. 64B to keep one slot per cacheline.
struct __align__(64) Rec {
    unsigned long long vbits;   // f64 bits of block-best distance
    int                idx;     // global point index of block winner
    float              cx, cy, cz;
    unsigned int       seq;     // published iteration tag (it+1)
    unsigned int       _pad[9];
};
#define NREC (2 * BATCH * G)    // 512 records, 32 KiB

// Zero the comm buffer. Separate kernel (not hipMemsetAsync) so that
// kernel_launch contains only plain kernel launches — maximally
// graph-capture-safe. Kernel-boundary implicit release makes these
// stores visible to fps_kernel on the same stream.
__global__ void init_comm(unsigned int* __restrict__ comm_u32) {
    const int n = NREC * (int)(sizeof(Rec) / 4);   // 8192 words
    for (int i = threadIdx.x; i < n; i += blockDim.x) comm_u32[i] = 0u;
}

// 256 blocks: bid%16 = batch, bid/16 = sub-block g. With default round-robin
// block->XCD (bid%8), all 16 blocks of a batch land on one XCD (perf only;
// correctness uses AGENT-scope atomics and holds under any placement).
// Each thread owns 8 consecutive points, coords pre-converted to f64 in
// registers; dist in registers. Compute phase touches no memory at all.
// Deadlock-safety: 256 blocks, __launch_bounds__(TPB,1) -> every CU hosts
// its block for the whole kernel; all blocks co-resident by construction.
__global__ __launch_bounds__(TPB, 1) void fps_kernel(
    const float* __restrict__ xyz,      // [B, N, 3]
    const int*   __restrict__ init_far, // [B]
    int*         __restrict__ fps_out,  // [B, NPOINT]
    Rec*         __restrict__ comm)     // [2][BATCH][G], zeroed by init_comm
{
#pragma clang fp contract(off)
    __shared__ double red_v[NWAVES];
    __shared__ int    red_i[NWAVES];
    __shared__ float  s_cx, s_cy, s_cz;

    const int bid  = blockIdx.x;
    const int b    = bid & (BATCH - 1);
    const int g    = bid >> 4;
    const int t    = threadIdx.x;
    const int lane = t & 63, wave = t >> 6;
    const float* xb = xyz + (size_t)b * NPT * 3;
    const int base = g * (TPB * PPT) + t * PPT;   // first owned point

    // one-time coord preload -> f64 registers (f32->f64 is exact)
    double px[PPT], py[PPT], pz[PPT];
    {
        float f[PPT * 3];
        const float4* v4 = (const float4*)(xb + (size_t)base * 3);  // 96B-aligned
        #pragma unroll
        for (int q = 0; q < (PPT * 3) / 4; ++q) {
            float4 x = v4[q];
            f[4*q+0] = x.x; f[4*q+1] = x.y; f[4*q+2] = x.z; f[4*q+3] = x.w;
        }
        #pragma unroll
        for (int j = 0; j < PPT; ++j) {
            px[j] = (double)f[3*j+0];
            py[j] = (double)f[3*j+1];
            pz[j] = (double)f[3*j+2];
        }
    }
    double dist[PPT];
    #pragma unroll
    for (int j = 0; j < PPT; ++j) dist[j] = 1e10;   // f64 1e10, matches np mirror

    const int far0 = init_far[b];
    double cx = (double)xb[far0 * 3 + 0];
    double cy = (double)xb[far0 * 3 + 1];
    double cz = (double)xb[far0 * 3 + 2];
    if (g == 0 && t == 0) fps_out[b * NPOINT] = far0;

    // iterations 0..NPOINT-2 (the last iteration of the scan records nothing)
    for (int it = 0; it < NPOINT - 1; ++it) {
        // ---- 1. register-resident distance update + per-thread argmax ----
        double best = -1.0; int bi = 0x7fffffff;
        #pragma unroll
        for (int j = 0; j < PPT; ++j) {
            // f64 mirror of np: d2 = (dx*dx + dy*dy) + dz*dz, no FMA
            double dx = px[j] - cx;
            double dy = py[j] - cy;
            double dz = pz[j] - cz;
            double d2 = (dx * dx + dy * dy) + dz * dz;
            double od = dist[j];
            double nd = (d2 < od) ? d2 : od;        // np.minimum (no NaNs)
            dist[j] = nd;
            // ascending index order -> strict > keeps lowest-index max
            bool took = nd > best;
            best = took ? nd : best;
            bi   = took ? base + j : bi;
        }
        // ---- 2. wave argmax, first-index tie-break ----
        #pragma unroll
        for (int off = 32; off >= 1; off >>= 1) {
            double ov = __shfl_xor(best, off);
            int    oi = __shfl_xor(bi,   off);
            if (ov > best || (ov == best && oi < bi)) { best = ov; bi = oi; }
        }
        if (lane == 0) { red_v[wave] = best; red_i[wave] = bi; }
        __syncthreads();
        // ---- 3. block argmax (redundant scan, uniform result) ----
        double bv = red_v[0]; int bidx = red_i[0];
        #pragma unroll
        for (int w = 1; w < NWAVES; ++w) {
            double v2 = red_v[w]; int i2 = red_i[w];
            if (v2 > bv || (v2 == bv && i2 < bidx)) { bv = v2; bidx = i2; }
        }
        // ---- 4. owner thread publishes block winner (+coords) ----
        Rec* wr = comm + (((it & 1) * BATCH + b) * G);
        const int lw = bidx - g * (TPB * PPT);      // local index in [0, 2048)
        if (t == (lw >> 3)) {
            double ox = px[0], oy = py[0], oz = pz[0];
            #pragma unroll
            for (int j = 1; j < PPT; ++j) {         // static-index select
                bool s = ((lw & 7) == j);
                ox = s ? px[j] : ox; oy = s ? py[j] : oy; oz = s ? pz[j] : oz;
            }
            Rec* r = wr + g;
            __hip_atomic_store(&r->vbits, (unsigned long long)__double_as_longlong(bv),
                               __ATOMIC_RELAXED, __HIP_MEMORY_SCOPE_AGENT);
            __hip_atomic_store(&r->idx, bidx, __ATOMIC_RELAXED, __HIP_MEMORY_SCOPE_AGENT);
            __hip_atomic_store(&r->cx, (float)ox, __ATOMIC_RELAXED, __HIP_MEMORY_SCOPE_AGENT);
            __hip_atomic_store(&r->cy, (float)oy, __ATOMIC_RELAXED, __HIP_MEMORY_SCOPE_AGENT);
            __hip_atomic_store(&r->cz, (float)oz, __ATOMIC_RELAXED, __HIP_MEMORY_SCOPE_AGENT);
            __hip_atomic_store(&r->seq, (unsigned)(it + 1),
                               __ATOMIC_RELEASE, __HIP_MEMORY_SCOPE_AGENT);
        }
        // ---- 5. wave 0: spin on all G winners, reduce, broadcast ----
        if (wave == 0) {
            double gv = -2.0; int gi = 0x7fffffff; float gx = 0.f, gy = 0.f, gz = 0.f;
            if (lane < G) {
                Rec* r = wr + lane;
                const unsigned tgt = (unsigned)(it + 1);
                while (__hip_atomic_load(&r->seq, __ATOMIC_ACQUIRE,
                                         __HIP_MEMORY_SCOPE_AGENT) != tgt) {
                    __builtin_amdgcn_s_sleep(1);   // ~64-cycle backoff
                }
                unsigned long long vb = __hip_atomic_load(&r->vbits, __ATOMIC_RELAXED,
                                                          __HIP_MEMORY_SCOPE_AGENT);
                gv = __longlong_as_double((long long)vb);
                gi = __hip_atomic_load(&r->idx, __ATOMIC_RELAXED, __HIP_MEMORY_SCOPE_AGENT);
                gx = __hip_atomic_load(&r->cx,  __ATOMIC_RELAXED, __HIP_MEMORY_SCOPE_AGENT);
                gy = __hip_atomic_load(&r->cy,  __ATOMIC_RELAXED, __HIP_MEMORY_SCOPE_AGENT);
                gz = __hip_atomic_load(&r->cz,  __ATOMIC_RELAXED, __HIP_MEMORY_SCOPE_AGENT);
            }
            #pragma unroll
            for (int off = 8; off >= 1; off >>= 1) {   // 16-lane reduce
                double ov = __shfl_xor(gv, off);
                int    oi = __shfl_xor(gi, off);
                float  ox = __shfl_xor(gx, off);
                float  oy = __shfl_xor(gy, off);
                float  oz = __shfl_xor(gz, off);
                if (ov > gv || (ov == gv && oi < gi)) {
                    gv = ov; gi = oi; gx = ox; gy = oy; gz = oz;
                }
            }
            if (lane == 0) {
                s_cx = gx; s_cy = gy; s_cz = gz;
                if (g == 0) fps_out[b * NPOINT + it + 1] = gi;
            }
        }
        __syncthreads();
        cx = (double)s_cx; cy = (double)s_cy; cz = (double)s_cz;  // exact f32->f64
    }
}

// Gather + transpose: out = [new_xyz (B,3,S) | new_features (B,C,S)], S=2048, C=128
__global__ void gather_kernel(const float* __restrict__ xyz,
                              const float* __restrict__ feat,
                              const int*   __restrict__ fps_idx,
                              float*       __restrict__ out)
{
    const int blk = blockIdx.x;
    const int s = blk & (NPOINT - 1);
    const int b = blk >> 11;
    const int idx = fps_idx[b * NPOINT + s];
    const int c = threadIdx.x;  // 128 threads
    const float v = feat[((size_t)(b * NPT + idx)) * 128 + c];
    out[(size_t)BATCH * 3 * NPOINT + ((size_t)(b * 128 + c)) * NPOINT + s] = v;
    if (c < 3) {
        out[((size_t)(b * 3 + c)) * NPOINT + s] =
            xyz[((size_t)(b * NPT + idx)) * 3 + c];
    }
}

extern "C" void kernel_launch(void* const* d_in, const int* in_sizes, int n_in,
                              void* d_out, int out_size, void* d_ws, size_t ws_size,
                              hipStream_t stream) {
    const float* xyz      = (const float*)d_in[0];  // [16, 32768, 3]
    const float* features = (const float*)d_in[1];  // [16, 32768, 128]
    const int*   init_far = (const int*)d_in[2];    // [16]
    float* out = (float*)d_out;
    int*   fps_idx = (int*)d_ws;                    // 128 KiB in workspace

    // Comm buffer lives in the head of d_out (32 KiB); gather_kernel fully
    // overwrites d_out afterwards (new_xyz region alone is 384 KiB), so this
    // is scratch-safe. init_comm zeroes it每 launch so stale seq tags can
    // never alias a live target (targets are 1..2047).
    Rec* comm = (Rec*)d_out;

    init_comm<<<1, 1024, 0, stream>>>((unsigned int*)comm);
    fps_kernel<<<BATCH * G, TPB, 0, stream>>>(xyz, init_far, fps_idx, comm);
    gather_kernel<<<BATCH * NPOINT, 128, 0, stream>>>(xyz, features, fps_idx, out);
}

// Round 4
// 8082.426 us; speedup vs baseline: 4.8912x; 2.8989x over previous
//
#include <hip/hip_runtime.h>

// Reference chain is numpy float64 (verified: absmax == 0 with exact f64 mirror).
// Distances/min/argmax computed in f64; no contraction anywhere.
#pragma clang fp contract(off)

#define BATCH  16
#define NPT    32768
#define NPOINT 2048
#define G      16            // blocks per batch
#define TPB    256
#define PPT    8             // points per thread; G*TPB*PPT == NPT
#define NWAVES (TPB/64)

// Cross-block message: 3 u64 words per (buf, batch, sub-block), one cacheline.
//   w0 = f64 bits of block-best distance
//   w1 = (cx_bits << 32) | cy_bits
//   w2 = (cz_bits << 32) | (idx & 0x7FFF) << 11 | tag(11b, = it+1, 1..2047)
//
// PROTOCOL (round-3 post-mortem — RMW-only, fence-free, hang-proof):
// All cross-block traffic uses RELAXED agent-scope atomic RMWs. An RMW must
// execute at the device coherent point (it cannot be served by a stale
// per-XCD L2), so polls are always fresh WITHOUT acquire's per-poll
// buffer_inv (round-2's 11.4us/iter cost) and publishes need no release
// wbl2. Ordering: producer exchanges w0,w1 (returning forms; returns kept
// alive so vmcnt tracks their LLC data-return), s_waitcnt vmcnt(0), then
// exchanges w2 with the tag. A consumer that observes the tag in w2 is
// therefore guaranteed w0/w1 are already at the coherent point, where its
// own RMW reads are served. No fences, no cache maintenance, no stale spin.
struct __align__(64) Rec {
    unsigned long long w0, w1, w2;
    unsigned long long _pad[5];
};
#define NREC (2 * BATCH * G)    // 512 records, 32 KiB

// Zero the comm buffer. Separate kernel (not hipMemsetAsync) — kernel_launch
// stays pure kernel launches (graph-capture-safe). Kernel-boundary implicit
// release makes these stores visible to fps_kernel. tag=0 never matches a
// live target (targets are 1..2047).
__global__ void init_comm(unsigned int* __restrict__ comm_u32) {
    const int n = NREC * (int)(sizeof(Rec) / 4);   // 8192 words
    for (int i = threadIdx.x; i < n; i += blockDim.x) comm_u32[i] = 0u;
}

// 256 blocks: bid%16 = batch, bid/16 = sub-block g. Each thread owns 8
// consecutive points, coords pre-converted to f64 registers; dist in
// registers. Compute phase touches no memory. Deadlock-safety: 256 blocks,
// __launch_bounds__(TPB,1) -> 1 block/CU on 256 CUs, all co-resident.
// Slot-reuse safety: parity p=it&1 slot written at it+2 only after its
// writer consumed iteration it+1, which required every block to have
// finished iteration it (i.e. consumed slot p's tag it+1) first.
__global__ __launch_bounds__(TPB, 1) void fps_kernel(
    const float* __restrict__ xyz,      // [B, N, 3]
    const int*   __restrict__ init_far, // [B]
    int*         __restrict__ fps_out,  // [B, NPOINT]
    Rec*         __restrict__ comm)     // [2][BATCH][G], zeroed by init_comm
{
#pragma clang fp contract(off)
    __shared__ double red_v[NWAVES];
    __shared__ int    red_i[NWAVES];
    __shared__ float  s_cx, s_cy, s_cz;

    const int bid  = blockIdx.x;
    const int b    = bid & (BATCH - 1);
    const int g    = bid >> 4;
    const int t    = threadIdx.x;
    const int lane = t & 63, wave = t >> 6;
    const float* xb = xyz + (size_t)b * NPT * 3;
    const int base = g * (TPB * PPT) + t * PPT;   // first owned point

    // one-time coord preload -> f64 registers (f32->f64 is exact)
    double px[PPT], py[PPT], pz[PPT];
    {
        float f[PPT * 3];
        const float4* v4 = (const float4*)(xb + (size_t)base * 3);  // 96B-aligned
        #pragma unroll
        for (int q = 0; q < (PPT * 3) / 4; ++q) {
            float4 x = v4[q];
            f[4*q+0] = x.x; f[4*q+1] = x.y; f[4*q+2] = x.z; f[4*q+3] = x.w;
        }
        #pragma unroll
        for (int j = 0; j < PPT; ++j) {
            px[j] = (double)f[3*j+0];
            py[j] = (double)f[3*j+1];
            pz[j] = (double)f[3*j+2];
        }
    }
    double dist[PPT];
    #pragma unroll
    for (int j = 0; j < PPT; ++j) dist[j] = 1e10;   // f64 1e10, matches np mirror

    const int far0 = init_far[b];
    double cx = (double)xb[far0 * 3 + 0];
    double cy = (double)xb[far0 * 3 + 1];
    double cz = (double)xb[far0 * 3 + 2];
    if (g == 0 && t == 0) fps_out[b * NPOINT] = far0;

    // iterations 0..NPOINT-2 (the last scan iteration records nothing)
    for (int it = 0; it < NPOINT - 1; ++it) {
        // ---- 1. register-resident distance update + per-thread argmax ----
        double best = -1.0; int bi = 0x7fffffff;
        #pragma unroll
        for (int j = 0; j < PPT; ++j) {
            // f64 mirror of np: d2 = (dx*dx + dy*dy) + dz*dz, no FMA
            double dx = px[j] - cx;
            double dy = py[j] - cy;
            double dz = pz[j] - cz;
            double d2 = (dx * dx + dy * dy) + dz * dz;
            double od = dist[j];
            double nd = (d2 < od) ? d2 : od;        // np.minimum (no NaNs)
            dist[j] = nd;
            // ascending index order -> strict > keeps lowest-index max
            bool took = nd > best;
            best = took ? nd : best;
            bi   = took ? base + j : bi;
        }
        // ---- 2. wave argmax, first-index tie-break ----
        #pragma unroll
        for (int off = 32; off >= 1; off >>= 1) {
            double ov = __shfl_xor(best, off);
            int    oi = __shfl_xor(bi,   off);
            if (ov > best || (ov == best && oi < bi)) { best = ov; bi = oi; }
        }
        if (lane == 0) { red_v[wave] = best; red_i[wave] = bi; }
        __syncthreads();
        // ---- 3. block argmax (redundant scan, uniform result) ----
        double bv = red_v[0]; int bidx = red_i[0];
        #pragma unroll
        for (int w = 1; w < NWAVES; ++w) {
            double v2 = red_v[w]; int i2 = red_i[w];
            if (v2 > bv || (v2 == bv && i2 < bidx)) { bv = v2; bidx = i2; }
        }
        // ---- 4. owner thread publishes block winner (packed, RMW-only) ----
        Rec* wr = comm + (((it & 1) * BATCH + b) * G);
        const int lw = bidx - g * (TPB * PPT);      // local index in [0, 2048)
        if (t == (lw >> 3)) {
            double ox = px[0], oy = py[0], oz = pz[0];
            #pragma unroll
            for (int j = 1; j < PPT; ++j) {         // static-index select
                bool s = ((lw & 7) == j);
                ox = s ? px[j] : ox; oy = s ? py[j] : oy; oz = s ? pz[j] : oz;
            }
            Rec* r = wr + g;
            const unsigned long long m0 =
                (unsigned long long)__double_as_longlong(bv);
            const unsigned long long m1 =
                ((unsigned long long)__float_as_uint((float)ox) << 32) |
                 (unsigned long long)__float_as_uint((float)oy);
            const unsigned long long m2 =
                ((unsigned long long)__float_as_uint((float)oz) << 32) |
                ((unsigned long long)(bidx & 0x7FFF) << 11) |
                 (unsigned long long)(unsigned)(it + 1);
            // returning exchanges: returns kept alive so vmcnt(0) waits for
            // LLC data-return == proof the RMWs executed at coherent point.
            unsigned long long o0 = __hip_atomic_exchange(
                &r->w0, m0, __ATOMIC_RELAXED, __HIP_MEMORY_SCOPE_AGENT);
            unsigned long long o1 = __hip_atomic_exchange(
                &r->w1, m1, __ATOMIC_RELAXED, __HIP_MEMORY_SCOPE_AGENT);
            asm volatile("" :: "v"(o0), "v"(o1));
            asm volatile("s_waitcnt vmcnt(0)" ::: "memory");
            unsigned long long o2 = __hip_atomic_exchange(
                &r->w2, m2, __ATOMIC_RELAXED, __HIP_MEMORY_SCOPE_AGENT);
            asm volatile("" :: "v"(o2));
        }
        // ---- 5. wave 0: RMW-poll all G winners, reduce, broadcast ----
        if (wave == 0) {
            double gv = -2.0; int gi = 0x7fffffff; float gx = 0.f, gy = 0.f, gz = 0.f;
            if (lane < G) {
                Rec* r = wr + lane;
                const unsigned tgt = (unsigned)(it + 1);
                unsigned long long w2v;
                for (;;) {
                    // RMW poll: executes at the coherent point, always fresh.
                    w2v = __hip_atomic_fetch_add(
                        &r->w2, 0ull, __ATOMIC_RELAXED, __HIP_MEMORY_SCOPE_AGENT);
                    if ((unsigned)(w2v & 0x7FFull) == tgt) break;
                    __builtin_amdgcn_s_sleep(1);   // ~64-cycle backoff
                }
                unsigned long long w0v = __hip_atomic_fetch_add(
                    &r->w0, 0ull, __ATOMIC_RELAXED, __HIP_MEMORY_SCOPE_AGENT);
                unsigned long long w1v = __hip_atomic_fetch_add(
                    &r->w1, 0ull, __ATOMIC_RELAXED, __HIP_MEMORY_SCOPE_AGENT);
                gv = __longlong_as_double((long long)w0v);
                gi = (int)((w2v >> 11) & 0x7FFFull);
                gx = __uint_as_float((unsigned)(w1v >> 32));
                gy = __uint_as_float((unsigned)(w1v & 0xffffffffull));
                gz = __uint_as_float((unsigned)(w2v >> 32));
            }
            #pragma unroll
            for (int off = 8; off >= 1; off >>= 1) {   // 16-lane reduce
                double ov = __shfl_xor(gv, off);
                int    oi = __shfl_xor(gi, off);
                float  ox = __shfl_xor(gx, off);
                float  oy = __shfl_xor(gy, off);
                float  oz = __shfl_xor(gz, off);
                if (ov > gv || (ov == gv && oi < gi)) {
                    gv = ov; gi = oi; gx = ox; gy = oy; gz = oz;
                }
            }
            if (lane == 0) {
                s_cx = gx; s_cy = gy; s_cz = gz;
                if (g == 0) fps_out[b * NPOINT + it + 1] = gi;
            }
        }
        __syncthreads();
        cx = (double)s_cx; cy = (double)s_cy; cz = (double)s_cz;  // exact f32->f64
    }
}

// Gather + transpose: out = [new_xyz (B,3,S) | new_features (B,C,S)], S=2048, C=128
__global__ void gather_kernel(const float* __restrict__ xyz,
                              const float* __restrict__ feat,
                              const int*   __restrict__ fps_idx,
                              float*       __restrict__ out)
{
    const int blk = blockIdx.x;
    const int s = blk & (NPOINT - 1);
    const int b = blk >> 11;
    const int idx = fps_idx[b * NPOINT + s];
    const int c = threadIdx.x;  // 128 threads
    const float v = feat[((size_t)(b * NPT + idx)) * 128 + c];
    out[(size_t)BATCH * 3 * NPOINT + ((size_t)(b * 128 + c)) * NPOINT + s] = v;
    if (c < 3) {
        out[((size_t)(b * 3 + c)) * NPOINT + s] =
            xyz[((size_t)(b * NPT + idx)) * 3 + c];
    }
}

extern "C" void kernel_launch(void* const* d_in, const int* in_sizes, int n_in,
                              void* d_out, int out_size, void* d_ws, size_t ws_size,
                              hipStream_t stream) {
    const float* xyz      = (const float*)d_in[0];  // [16, 32768, 3]
    const float* features = (const float*)d_in[1];  // [16, 32768, 128]
    const int*   init_far = (const int*)d_in[2];    // [16]
    float* out = (float*)d_out;
    int*   fps_idx = (int*)d_ws;                    // 128 KiB in workspace

    // Comm buffer lives in the head of d_out (32 KiB); gather_kernel fully
    // overwrites d_out afterwards, so this is scratch-safe. init_comm zeroes
    // it each launch so stale tags never alias live targets (1..2047).
    Rec* comm = (Rec*)d_out;

    init_comm<<<1, 1024, 0, stream>>>((unsigned int*)comm);
    fps_kernel<<<BATCH * G, TPB, 0, stream>>>(xyz, init_far, fps_idx, comm);
    gather_kernel<<<BATCH * NPOINT, 128, 0, stream>>>(xyz, features, fps_idx, out);
}